// Round 10
// baseline (631.860 us; speedup 1.0000x reference)
//
#include <hip/hip_runtime.h>
#include <hip/hip_bf16.h>

#define N_VOCAB 50257
#define NBC     786     // n-block columns (64 wide)
#define N_PAD   50304   // 786 * 64
#define D_K     1024
#define M_ROWS  2048
#define MT      32                  // m-tiles (2048/64)
#define GEMM_BLOCKS (NBC * MT)      // 25152 = 8 * 3144
#define PER_XCD     (GEMM_BLOCKS/8) // 3144

typedef __attribute__((ext_vector_type(4))) int i32x4;

__device__ inline void async_copy16(const void* g, void* l) {
  auto* gp = (const __attribute__((address_space(1))) unsigned int*)g;
  auto* lp = (__attribute__((address_space(3))) unsigned int*)l;
  __builtin_amdgcn_global_load_lds(gp, lp, 16, 0, 0);
}

__device__ inline signed char qint(float v, float s) {
  float q = fminf(fmaxf(rintf(v / s), -8.f), 7.f);
  return (signed char)(int)q;
}

// ---------------- fused absmax (x -> amax[0], W -> amax[1]) ----------------
__global__ void absmax2_kernel(const float4* __restrict__ x, int nx4,
                               const float4* __restrict__ Wp, int nw4,
                               unsigned* __restrict__ amax) {
  const bool isx = blockIdx.x < 512;
  const float4* p = isx ? x : Wp;
  const int n4 = isx ? nx4 : nw4;
  const int b0 = isx ? blockIdx.x : blockIdx.x - 512;
  const int nb = isx ? 512 : (gridDim.x - 512);
  float m = 0.f;
  for (int i = b0 * blockDim.x + threadIdx.x; i < n4; i += nb * blockDim.x) {
    float4 v = p[i];
    m = fmaxf(m, fmaxf(fmaxf(fabsf(v.x), fabsf(v.y)),
                       fmaxf(fabsf(v.z), fabsf(v.w))));
  }
#pragma unroll
  for (int off = 32; off; off >>= 1) m = fmaxf(m, __shfl_xor(m, off));
  __shared__ float red[4];
  int tid = threadIdx.x;
  if ((tid & 63) == 0) red[tid >> 6] = m;
  __syncthreads();
  if (tid == 0) {
    m = fmaxf(fmaxf(red[0], red[1]), fmaxf(red[2], red[3]));
    atomicMax(&amax[isx ? 0 : 1], __float_as_uint(m));
  }
}

// ---------------- fused quantize x, W, bias ----------------
__global__ void quant_kernel(const float4* __restrict__ x,
                             const float4* __restrict__ Wp,
                             const float* __restrict__ b,
                             char4* __restrict__ qx, char4* __restrict__ qw,
                             float* __restrict__ bq,
                             const unsigned* __restrict__ amax) {
  const int bid = blockIdx.x;
  const int tid = threadIdx.x;
  const int nw4 = (N_VOCAB * D_K) / 4;
  if (bid < 2048) {
    int i = bid * 256 + tid;
    float s = __uint_as_float(amax[0]) * (1.0f / 7.0f);
    float4 v = x[i];
    char4 q;
    q.x = qint(v.x, s); q.y = qint(v.y, s);
    q.z = qint(v.z, s); q.w = qint(v.w, s);
    qx[i] = q;
  } else if (bid < 2048 + 50304) {
    int i = (bid - 2048) * 256 + tid;
    char4 q = {0, 0, 0, 0};
    if (i < nw4) {
      float s = __uint_as_float(amax[1]) * (1.0f / 7.0f);
      float4 v = Wp[i];
      q.x = qint(v.x, s); q.y = qint(v.y, s);
      q.z = qint(v.z, s); q.w = qint(v.w, s);
    }
    qw[i] = q;
  } else {
    int i = (bid - (2048 + 50304)) * 256 + tid;
    if (i < N_PAD) {
      float v = 0.f;
      if (i < N_VOCAB) {
        float sb = (__uint_as_float(amax[0]) * (1.0f / 7.0f)) *
                   (__uint_as_float(amax[1]) * (1.0f / 7.0f));
        v = rintf(b[i] / sb) * sb;
      }
      bq[i] = v;
    }
  }
}

// ---------------- int8 GEMM, 1-wave 64x64 blocks, ZERO barriers ----------
// Each block = ONE wave computing a 64x64 output tile (acc 4x4, 16 MFMA per
// BK=64 K-step, NT=16). LDS = 2 x (4KB A + 4KB B) = 16 KB -> 10 blocks/CU,
// all independent (no s_barrier anywhere). Wave-internal pipeline:
// {vmcnt(8): tile kt staged -> ds_read 8 frags -> lgkmcnt(0) -> stage tile
// kt+2 into freed buffer -> 16 MFMA}. Counted vmcnt never drains mid-loop.
// 8-start XOR swizzle (0 conflicts, verified R5). mfma_i32_16x16x64_i8.
// XCD-bijective grid: a column's 32 m-blocks run consecutively on one XCD
// so its 64KB B panel stays L2-resident. Softmax partials via pure 16-lane
// shuffles (no LDS).
__global__ __launch_bounds__(64, 2) void gemm_kernel(
    const signed char* __restrict__ qx,   // [2048][1024]
    const signed char* __restrict__ qw,   // [50304][1024]
    const float* __restrict__ bq,         // [50304]
    const unsigned* __restrict__ amax,
    float* __restrict__ outp,             // [2048][50257]
    float* __restrict__ pmax,             // [2048][NBC]
    float* __restrict__ psum)             // [2048][NBC]
{
  constexpr int BK = 64;
  constexpr int NT = D_K / BK;  // 16
  __shared__ __align__(16) signed char sA[2][64 * BK];  // 8 KB
  __shared__ __align__(16) signed char sB[2][64 * BK];  // 8 KB

  const int l = threadIdx.x & 63;

  const int bid = blockIdx.x;
  const int vb = (bid & 7) * PER_XCD + (bid >> 3);
  const int nb = vb >> 5;          // 0..785 (column tile)
  const int m0 = (vb & 31) * 64;   // m tile
  const int n0 = nb * 64;

  const float sx = __uint_as_float(amax[0]) * (1.0f / 7.0f);
  const float sw = __uint_as_float(amax[1]) * (1.0f / 7.0f);
  const float scale = sx * sw;

  i32x4 acc[4][4] = {};

  // staging: chunk c (0..3) = 16 rows x 64B; lane l -> row c*16 + (l>>2),
  // source k-slot pre-swizzled (slot ^ ((row>>1)&3) = (l&3)^((l>>3)&3));
  // LDS dest linear (lane*16).
  const int srow = l >> 2;
  const int scol = ((l & 3) ^ ((l >> 3) & 3)) * 16;

  auto stage = [&](int buf, int kt) {
    int k0 = kt * BK;
#pragma unroll
    for (int c = 0; c < 4; ++c) {
      int row = c * 16 + srow;
      async_copy16(qx + (size_t)(m0 + row) * D_K + k0 + scol,
                   &sA[buf][c * 1024]);
    }
#pragma unroll
    for (int c = 0; c < 4; ++c) {
      int row = c * 16 + srow;
      async_copy16(qw + (size_t)(n0 + row) * D_K + k0 + scol,
                   &sB[buf][c * 1024]);
    }
  };

  // prologue: tiles 0 and 1 in flight (8 loads each)
  stage(0, 0);
  stage(1, 1);

#pragma unroll
  for (int kt = 0; kt < NT; ++kt) {
    const int cur = kt & 1;

    // tile kt ready (8 oldest retired); kt+1's 8 stay in flight
    if (kt + 1 < NT)
      asm volatile("s_waitcnt vmcnt(8)" ::: "memory");
    else
      asm volatile("s_waitcnt vmcnt(0)" ::: "memory");
    __builtin_amdgcn_sched_barrier(0);

    i32x4 af[4], bfr[4];
#pragma unroll
    for (int mi = 0; mi < 4; ++mi) {
      int row = mi * 16 + (l & 15);
      int kb = ((l >> 4) ^ ((row >> 1) & 3)) * 16;
      af[mi] = *(const i32x4*)&sA[cur][row * BK + kb];
    }
#pragma unroll
    for (int ni = 0; ni < 4; ++ni) {
      int row = ni * 16 + (l & 15);
      int kb = ((l >> 4) ^ ((row >> 1) & 3)) * 16;
      bfr[ni] = *(const i32x4*)&sB[cur][row * BK + kb];
    }
    // all 8 frags in regs before overwriting this buffer
    asm volatile("s_waitcnt lgkmcnt(0)" ::: "memory");
    __builtin_amdgcn_sched_barrier(0);

    if (kt + 2 < NT) stage(cur, kt + 2);
    __builtin_amdgcn_sched_barrier(0);

#pragma unroll
    for (int mi = 0; mi < 4; ++mi)
#pragma unroll
      for (int ni = 0; ni < 4; ++ni)
        acc[mi][ni] = __builtin_amdgcn_mfma_i32_16x16x64_i8(
            af[mi], bfr[ni], acc[mi][ni], 0, 0, 0);
  }

  // ---- epilogue: scale + bias, softmax partials (pure shuffles) ----
  bool valid[4];
  float bb[4];
#pragma unroll
  for (int ni = 0; ni < 4; ++ni) {
    int col = n0 + ni * 16 + (l & 15);
    valid[ni] = (col < N_VOCAB);
    bb[ni] = valid[ni] ? bq[col] : 0.f;
  }
  float lg[4][4][4];
#pragma unroll
  for (int mi = 0; mi < 4; ++mi)
#pragma unroll
    for (int ni = 0; ni < 4; ++ni)
#pragma unroll
      for (int r = 0; r < 4; ++r)
        lg[mi][ni][r] = (float)acc[mi][ni][r] * scale + bb[ni];

#pragma unroll
  for (int mi = 0; mi < 4; ++mi)
#pragma unroll
    for (int r = 0; r < 4; ++r) {
      float mval = -3.4e38f;
#pragma unroll
      for (int ni = 0; ni < 4; ++ni)
        if (valid[ni]) mval = fmaxf(mval, lg[mi][ni][r]);
#pragma unroll
      for (int off = 1; off < 16; off <<= 1)
        mval = fmaxf(mval, __shfl_xor(mval, off));
      float s = 0.f;
#pragma unroll
      for (int ni = 0; ni < 4; ++ni)
        if (valid[ni]) s += __expf(lg[mi][ni][r] - mval);
#pragma unroll
      for (int off = 1; off < 16; off <<= 1)
        s += __shfl_xor(s, off);
      if ((l & 15) == 0) {
        int rowg = m0 + mi * 16 + (l >> 4) * 4 + r;
        pmax[(size_t)rowg * NBC + nb] = mval;
        psum[(size_t)rowg * NBC + nb] = s;
      }
    }

  // ---- direct logit store, row-grouped ----
#pragma unroll
  for (int mi = 0; mi < 4; ++mi)
#pragma unroll
    for (int r = 0; r < 4; ++r) {
      int rowg = m0 + mi * 16 + (l >> 4) * 4 + r;
      size_t rb = (size_t)rowg * N_VOCAB;
#pragma unroll
      for (int ni = 0; ni < 4; ++ni) {
        if (valid[ni]) {
          int col = n0 + ni * 16 + (l & 15);
          outp[rb + col] = lg[mi][ni][r];
        }
      }
    }
}

// ---------------- merged: per-row logZ + subtract (2 blocks per row) --------
__global__ __launch_bounds__(256) void logz_sub_kernel(
    const float* __restrict__ pmax, const float* __restrict__ psum,
    float* __restrict__ out) {
  const int row = blockIdx.x >> 1;
  const int half = blockIdx.x & 1;
  const float* pm = pmax + (size_t)row * NBC;
  const float* ps = psum + (size_t)row * NBC;
  const int tid = threadIdx.x;
  __shared__ float red[9];

  float m = -3.4e38f;
  for (int i = tid; i < NBC; i += 256) m = fmaxf(m, pm[i]);
#pragma unroll
  for (int off = 32; off; off >>= 1) m = fmaxf(m, __shfl_xor(m, off));
  if ((tid & 63) == 0) red[tid >> 6] = m;
  __syncthreads();
  m = fmaxf(fmaxf(red[0], red[1]), fmaxf(red[2], red[3]));

  float s = 0.f;
  for (int i = tid; i < NBC; i += 256) s += ps[i] * __expf(pm[i] - m);
#pragma unroll
  for (int off = 32; off; off >>= 1) s += __shfl_xor(s, off);
  if ((tid & 63) == 0) red[4 + (tid >> 6)] = s;
  __syncthreads();
  if (tid == 0) {
    s = red[4] + red[5] + red[6] + red[7];
    red[8] = m + __logf(s);
  }
  __syncthreads();
  const float lz = red[8];

  // subtract in place; this block handles its half of the row
  const size_t base = (size_t)row * N_VOCAB;
  const int a = (4 - (row & 3)) & 3;  // head scalars to align to 16B
  const int n4 = (N_VOCAB - a) >> 2;  // aligned float4 count
  const int h4 = (n4 + 1) >> 1;       // per-half float4s
  const int i0 = half * h4;
  const int i1 = min(n4, i0 + h4);
  float4* p = (float4*)(out + base + a);
  for (int i = i0 + tid; i < i1; i += 256) {
    float4 v = p[i];
    v.x -= lz; v.y -= lz; v.z -= lz; v.w -= lz;
    p[i] = v;
  }
  if (half == 0) {
    if (tid < a) out[base + tid] -= lz;
  } else {
    const int done = a + n4 * 4;
    if (tid < N_VOCAB - done) out[base + done + tid] -= lz;
  }
}

extern "C" void kernel_launch(void* const* d_in, const int* in_sizes, int n_in,
                              void* d_out, int out_size, void* d_ws,
                              size_t ws_size, hipStream_t stream) {
  const float* x = (const float*)d_in[0];
  const float* W = (const float*)d_in[1];
  const float* b = (const float*)d_in[2];
  float* out = (float*)d_out;

  char* ws = (char*)d_ws;
  unsigned* amax = (unsigned*)ws;                        // 8 B
  float* bq = (float*)(ws + 4096);                       // 202 KB
  float* pmax = (float*)(ws + (1ull << 20));             // 6.44 MB
  float* psum = (float*)(ws + (8ull << 20));             // 6.44 MB
  signed char* qx = (signed char*)(ws + (15ull << 20));  // 2 MB
  signed char* qw = (signed char*)(ws + (17ull << 20));  // 51.5 MB (ends ~68.5)

  hipMemsetAsync(amax, 0, 8, stream);

  const int nx4 = (M_ROWS * D_K) / 4;   // 524288
  const int nw4 = (N_VOCAB * D_K) / 4;  // 12865792

  absmax2_kernel<<<2560, 256, 0, stream>>>((const float4*)x, nx4,
                                           (const float4*)W, nw4, amax);

  quant_kernel<<<2048 + 50304 + 197, 256, 0, stream>>>(
      (const float4*)x, (const float4*)W, b, (char4*)qx, (char4*)qw, bq, amax);

  gemm_kernel<<<GEMM_BLOCKS, 64, 0, stream>>>(qx, qw, bq, amax, out, pmax,
                                              psum);

  logz_sub_kernel<<<M_ROWS * 2, 256, 0, stream>>>(pmax, psum, out);
}